// Round 1
// 584.339 us; speedup vs baseline: 1.0949x; 1.0949x over previous
//
#include <hip/hip_runtime.h>
#include <cstddef>

#define BB 2048
#define TT 200
#define HH 256
#define KK 8

// workspace layout (in floats)
#define WS_M2T  0        // 257 rows x 256 (row 256 = dvec = Wk@bq)
#define WS_EVEC 65792    // 256  (Wq@bk)
#define WS_F    66048    // 1    (bk.bq)

__device__ __forceinline__ float wred_sum(float v) {
#pragma unroll
  for (int off = 32; off; off >>= 1) v += __shfl_xor(v, off);
  return v;
}
__device__ __forceinline__ float wred_max(float v) {
#pragma unroll
  for (int off = 32; off; off >>= 1) v = fmaxf(v, __shfl_xor(v, off));
  return v;
}

// ---------------------------------------------------------------------------
// prep_all: blocks 0..15 = 64x64 tiles of M2T[l][i] = sum_j Wq[l][j]*Wk[i][j];
// blocks 16..271: M2T row 256 = Wk@bq; 272..527: evec = Wq@bk; 528: fsc = bk.bq
// ---------------------------------------------------------------------------
__global__ __launch_bounds__(256) void prep_all(
    const float* __restrict__ Wq, const float* __restrict__ bq,
    const float* __restrict__ Wk, const float* __restrict__ bk,
    float* __restrict__ M2T, float* __restrict__ evec, float* __restrict__ fsc) {
  const int tid = threadIdx.x;
  __shared__ float As[64][68], Bs[64][68];
  __shared__ float s4[4];
  if (blockIdx.x < 16) {
    const int l0 = ((int)blockIdx.x >> 2) * 64, i0 = ((int)blockIdx.x & 3) * 64;
    const int tl = tid >> 4, ti = tid & 15;
    float acc[4][4];
#pragma unroll
    for (int r = 0; r < 4; ++r)
#pragma unroll
      for (int c = 0; c < 4; ++c) acc[r][c] = 0.f;

    for (int kc = 0; kc < 4; ++kc) {
      const int k0 = kc * 64;
#pragma unroll
      for (int it = 0; it < 4; ++it) {
        int idx = it * 256 + tid;
        int row = idx >> 4, c4 = idx & 15;
        *(float4*)(&As[row][c4 * 4]) =
            *(const float4*)(Wq + (size_t)(l0 + row) * HH + k0 + c4 * 4);
        *(float4*)(&Bs[row][c4 * 4]) =
            *(const float4*)(Wk + (size_t)(i0 + row) * HH + k0 + c4 * 4);
      }
      __syncthreads();
#pragma unroll 4
      for (int k4 = 0; k4 < 16; ++k4) {
        float4 a4[4], b4[4];
#pragma unroll
        for (int r = 0; r < 4; ++r) a4[r] = *(const float4*)(&As[tl * 4 + r][k4 * 4]);
#pragma unroll
        for (int c = 0; c < 4; ++c) b4[c] = *(const float4*)(&Bs[ti * 4 + c][k4 * 4]);
#pragma unroll
        for (int r = 0; r < 4; ++r)
#pragma unroll
          for (int c = 0; c < 4; ++c)
            acc[r][c] += a4[r].x * b4[c].x + a4[r].y * b4[c].y +
                         a4[r].z * b4[c].z + a4[r].w * b4[c].w;
      }
      __syncthreads();
    }
#pragma unroll
    for (int r = 0; r < 4; ++r) {
      float4 o = make_float4(acc[r][0], acc[r][1], acc[r][2], acc[r][3]);
      *(float4*)(M2T + (size_t)(l0 + tl * 4 + r) * HH + i0 + ti * 4) = o;
    }
  } else {
    const int id = (int)blockIdx.x - 16;
    const float* row;
    const float* vec;
    float* outp;
    if (id < 256)      { row = Wk + (size_t)id * HH;         vec = bq; outp = M2T + (size_t)256 * HH + id; }
    else if (id < 512) { row = Wq + (size_t)(id - 256) * HH; vec = bk; outp = evec + (id - 256); }
    else               { row = bk;                           vec = bq; outp = fsc; }
    float p = row[tid] * vec[tid];
    p = wred_sum(p);
    if ((tid & 63) == 0) s4[tid >> 6] = p;
    __syncthreads();
    if (tid == 0) *outp = s4[0] + s4[1] + s4[2] + s4[3];
  }
}

// ---------------------------------------------------------------------------
// fused_attn: one block per b.  Phases:
//  0: cs->LDS, mask count, qb partial
//  1: QK row inline from M2T (wave-split over l, LDS combine)  [was qkg]
//  2: scores (8 rows in flight per wave)
//  3: masked softmax + top-8
//  4: attn/selected outputs + gather 8 rows to LDS
//  5: Wv GEMV epilogue: col-split per wave, k-residue split per 16-lane
//     group -> Wv read exactly once per block (256KB, L2)       [was summ]
// ---------------------------------------------------------------------------
__global__ __launch_bounds__(256, 4) void fused_attn(
    const float* __restrict__ CS, const float* __restrict__ X,
    const int* __restrict__ VM,
    const float* __restrict__ M2T, const float* __restrict__ evec,
    const float* __restrict__ fsc,
    const float* __restrict__ Wv, const float* __restrict__ bvv,
    float* __restrict__ out) {
  const int tid = threadIdx.x, b = blockIdx.x;
  const int w = tid >> 6, lane = tid & 63;
  __shared__ float s_cs[HH];
  __shared__ float s_qk[HH];
  __shared__ float s_part[4][HH];
  __shared__ float s_sc[TT], s_cand[TT];
  __shared__ int   s_hist[TT];
  __shared__ float s_c4[4], s_r4[4], s_m4[4];
  __shared__ int   s_selI[KK];
  __shared__ float s_selV[KK];
  __shared__ float s_dS;
  __shared__ float s_xg[KK][HH + 4];

  // ---- phase 0: cs -> LDS, mask + count, qb partial ----
  const float csv = CS[(size_t)b * HH + tid];
  s_cs[tid] = csv;
  int m = (tid < TT) ? (VM[(size_t)b * TT + tid] != 0) : 0;
  unsigned long long bal = __ballot(m);
  if (lane == 0) s_c4[w] = (float)__popcll(bal);
  float rq = csv * evec[tid];
  rq = wred_sum(rq);
  if (lane == 0) s_r4[w] = rq;
  __syncthreads();

  const int cnt = (int)(s_c4[0] + s_c4[1] + s_c4[2] + s_c4[3]);
  const int hist_n = cnt - 1;            // score rows t in [0, hist_n)
  if (tid < TT) s_hist[tid] = (m && (tid < hist_n)) ? 1 : 0;
  const float qb = (s_r4[0] + s_r4[1] + s_r4[2] + s_r4[3] + fsc[0]) * 0.0625f;

  // ---- phase 1: QK[i] = (sum_l cs[l]*M2T[l][i] + dvec[i]) / 16 ----
  {
    float4 acc4 = make_float4(0.f, 0.f, 0.f, 0.f);
    const int l0 = w * 64;
    const float* mbase = M2T + (size_t)l0 * HH + lane * 4;
#pragma unroll 8
    for (int li = 0; li < 64; ++li) {
      const float a = s_cs[l0 + li];
      const float4 m4 = *(const float4*)(mbase + (size_t)li * HH);
      acc4.x += a * m4.x; acc4.y += a * m4.y;
      acc4.z += a * m4.z; acc4.w += a * m4.w;
    }
    *(float4*)(&s_part[w][lane * 4]) = acc4;
  }
  __syncthreads();
  {
    const float qk = s_part[0][tid] + s_part[1][tid] + s_part[2][tid] +
                     s_part[3][tid] + M2T[(size_t)256 * HH + tid];
    s_qk[tid] = qk * 0.0625f;
  }
  __syncthreads();

  // ---- phase 2: scores, wave w owns t = w, w+4, ...; 8 rows in flight ----
  {
    const float* xrow = X + (size_t)b * TT * HH + lane * 4;
    const float4 q4 = ((const float4*)s_qk)[lane];
    int t = w;
    for (; t + 28 < hist_n; t += 32) {
      float4 xv[8];
#pragma unroll
      for (int j = 0; j < 8; ++j)
        xv[j] = *(const float4*)(xrow + (size_t)(t + 4 * j) * HH);
      float pr[8];
#pragma unroll
      for (int j = 0; j < 8; ++j)
        pr[j] = xv[j].x * q4.x + xv[j].y * q4.y + xv[j].z * q4.z + xv[j].w * q4.w;
#pragma unroll
      for (int off = 32; off; off >>= 1)
#pragma unroll
        for (int j = 0; j < 8; ++j) pr[j] += __shfl_xor(pr[j], off);
      if (lane == 0) {
#pragma unroll
        for (int j = 0; j < 8; ++j) s_sc[t + 4 * j] = pr[j] + qb;
      }
    }
    for (; t < hist_n; t += 4) {
      float4 xv = *(const float4*)(xrow + (size_t)t * HH);
      float p = xv.x * q4.x + xv.y * q4.y + xv.z * q4.z + xv.w * q4.w;
      p = wred_sum(p);
      if (lane == 0) s_sc[t] = p + qb;
    }
  }
  __syncthreads();

  // ---- phase 3a: masked softmax ----
  const int hist = (tid < TT) ? s_hist[tid] : 0;
  float v = hist ? s_sc[tid] : -3.4e38f;
  float wm = wred_max(v);
  if (lane == 0) s_m4[w] = wm;
  __syncthreads();
  const float mx = fmaxf(fmaxf(s_m4[0], s_m4[1]), fmaxf(s_m4[2], s_m4[3]));
  float p = hist ? expf(v - mx) : 0.f;
  float ws_ = wred_sum(p);
  if (lane == 0) s_r4[w] = ws_;
  __syncthreads();
  const float denom = s_r4[0] + s_r4[1] + s_r4[2] + s_r4[3];
  if (tid < TT) s_cand[tid] = hist ? (p / denom) : -1.0f;
  __syncthreads();

  // ---- phase 3b: top-8 (wave 0): value desc, index asc ----
  if (tid < 64) {
    float lv[4]; int lt[4];
#pragma unroll
    for (int q = 0; q < 4; ++q) {
      int t = tid + 64 * q;
      lv[q] = (t < TT) ? s_cand[t] : -2.0f;
      lt[q] = t;
    }
    for (int r = 0; r < KK; ++r) {
      float bv = -2.5f; int bi = 1 << 30;
#pragma unroll
      for (int q = 0; q < 4; ++q)
        if (lv[q] > bv) { bv = lv[q]; bi = lt[q]; }
#pragma unroll
      for (int off = 32; off; off >>= 1) {
        float ov = __shfl_xor(bv, off);
        int   oi = __shfl_xor(bi, off);
        if (ov > bv || (ov == bv && oi < bi)) { bv = ov; bi = oi; }
      }
      if (tid == 0) { s_selI[r] = bi; s_selV[r] = bv; }
#pragma unroll
      for (int q = 0; q < 4; ++q)
        if (lt[q] == bi) lv[q] = -3.0f;
    }
    if (tid == 0) {
      float S = 0.f;
#pragma unroll
      for (int r = 0; r < KK; ++r) S += fmaxf(s_selV[r], 0.f);
      s_dS = fmaxf(S, 1.1920929e-07f);
    }
  }
  __syncthreads();

  // ---- phase 4: zero attn row + gather selected rows to LDS ----
  float* out_attn = out + (size_t)BB * HH + (size_t)b * TT;
  if (tid < TT) out_attn[tid] = 0.f;
#pragma unroll
  for (int it = 0; it < 2; ++it) {
    const int r = it * 4 + (tid >> 6);
    const int t = (s_selV[r] >= 0.f) ? s_selI[r] : 0;
    const int c0 = (tid & 63) * 4;
    *(float4*)(&s_xg[r][c0]) =
        *(const float4*)(X + ((size_t)b * TT + t) * HH + c0);
  }
  __syncthreads();

  if (tid < KK) {
    float vvv = s_selV[tid];
    int   bi  = s_selI[tid];
    float wf  = fmaxf(vvv, 0.f) / s_dS;
    int ok = (vvv >= 0.f);
    if (ok) out_attn[bi] = wf;
    out[(size_t)BB * HH + (size_t)BB * TT + (size_t)b * KK + tid] =
        ok ? (float)bi : -1.0f;
  }

  // ---- phase 5: summary = sum_r w_r * relu(xg[r] @ Wv + bv) ----
  // wave w owns output cols [w*64, w*64+64); lane = kk*16 + c16:
  // lane covers cols w*64 + c16*4 .. +3, k residue class kk (mod 4).
  {
    const int kk = lane >> 4, c16 = lane & 15;
    const float* wvbase = Wv + w * 64 + c16 * 4;
    float4 acc[KK];
#pragma unroll
    for (int r = 0; r < KK; ++r) acc[r] = make_float4(0.f, 0.f, 0.f, 0.f);
#pragma unroll 4
    for (int kb = 0; kb < 64; ++kb) {
      const int k = kb * 4 + kk;
      const float4 wv4 = *(const float4*)(wvbase + (size_t)k * HH);
#pragma unroll
      for (int r = 0; r < KK; ++r) {
        const float xv = s_xg[r][k];
        acc[r].x += xv * wv4.x; acc[r].y += xv * wv4.y;
        acc[r].z += xv * wv4.z; acc[r].w += xv * wv4.w;
      }
    }
    // combine the 4 k-residue groups (lanes c16, c16+16, c16+32, c16+48)
#pragma unroll
    for (int r = 0; r < KK; ++r) {
      acc[r].x += __shfl_xor(acc[r].x, 16); acc[r].x += __shfl_xor(acc[r].x, 32);
      acc[r].y += __shfl_xor(acc[r].y, 16); acc[r].y += __shfl_xor(acc[r].y, 32);
      acc[r].z += __shfl_xor(acc[r].z, 16); acc[r].z += __shfl_xor(acc[r].z, 32);
      acc[r].w += __shfl_xor(acc[r].w, 16); acc[r].w += __shfl_xor(acc[r].w, 32);
    }
    if (lane < 16) {
      const float4 bv4 = *(const float4*)(bvv + w * 64 + c16 * 4);
      float4 res = make_float4(0.f, 0.f, 0.f, 0.f);
#pragma unroll
      for (int r = 0; r < KK; ++r) {
        const float wr = fmaxf(s_selV[r], 0.f) / s_dS;
        res.x += wr * fmaxf(acc[r].x + bv4.x, 0.f);
        res.y += wr * fmaxf(acc[r].y + bv4.y, 0.f);
        res.z += wr * fmaxf(acc[r].z + bv4.z, 0.f);
        res.w += wr * fmaxf(acc[r].w + bv4.w, 0.f);
      }
      *(float4*)(out + (size_t)b * HH + w * 64 + c16 * 4) = res;
    }
  }
}

// ---------------------------------------------------------------------------
extern "C" void kernel_launch(void* const* d_in, const int* in_sizes, int n_in,
                              void* d_out, int out_size, void* d_ws, size_t ws_size,
                              hipStream_t stream) {
  const float* cs  = (const float*)d_in[0];
  const float* X   = (const float*)d_in[1];
  const int*   vm  = (const int*)d_in[2];
  const float* Wq  = (const float*)d_in[3];
  const float* bq  = (const float*)d_in[4];
  const float* Wk  = (const float*)d_in[5];
  const float* bk  = (const float*)d_in[6];
  const float* Wv  = (const float*)d_in[7];
  const float* bvp = (const float*)d_in[8];
  float* out = (float*)d_out;
  float* ws  = (float*)d_ws;

  float* M2T  = ws + WS_M2T;
  float* evec = ws + WS_EVEC;
  float* fsc  = ws + WS_F;

  hipLaunchKernelGGL(prep_all, dim3(529), dim3(256), 0, stream,
                     Wq, bq, Wk, bk, M2T, evec, fsc);
  hipLaunchKernelGGL(fused_attn, dim3(BB), dim3(256), 0, stream,
                     cs, X, vm, M2T, evec, fsc, Wv, bvp, out);
}

// Round 2
// 563.905 us; speedup vs baseline: 1.1345x; 1.0362x over previous
//
#include <hip/hip_runtime.h>
#include <cstddef>

#define BB 2048
#define TT 200
#define HH 256
#define KK 8

// workspace layout (in floats)
#define WS_M2T  0        // 257 rows x 256 (row 256 = dvec = Wk@bq)
#define WS_EVEC 65792    // 256  (Wq@bk)
#define WS_F    66048    // 1    (bk.bq)

__device__ __forceinline__ float wred_sum(float v) {
#pragma unroll
  for (int off = 32; off; off >>= 1) v += __shfl_xor(v, off);
  return v;
}
__device__ __forceinline__ float wred_max(float v) {
#pragma unroll
  for (int off = 32; off; off >>= 1) v = fmaxf(v, __shfl_xor(v, off));
  return v;
}

// ---------------------------------------------------------------------------
// prep_all: blocks 0..15 = 64x64 tiles of M2T[l][i] = sum_j Wq[l][j]*Wk[i][j];
// blocks 16..271: M2T row 256 = Wk@bq; 272..527: evec = Wq@bk; 528: fsc = bk.bq
// ---------------------------------------------------------------------------
__global__ __launch_bounds__(256) void prep_all(
    const float* __restrict__ Wq, const float* __restrict__ bq,
    const float* __restrict__ Wk, const float* __restrict__ bk,
    float* __restrict__ M2T, float* __restrict__ evec, float* __restrict__ fsc) {
  const int tid = threadIdx.x;
  __shared__ float As[64][68], Bs[64][68];
  __shared__ float s4[4];
  if (blockIdx.x < 16) {
    const int l0 = ((int)blockIdx.x >> 2) * 64, i0 = ((int)blockIdx.x & 3) * 64;
    const int tl = tid >> 4, ti = tid & 15;
    float acc[4][4];
#pragma unroll
    for (int r = 0; r < 4; ++r)
#pragma unroll
      for (int c = 0; c < 4; ++c) acc[r][c] = 0.f;

    for (int kc = 0; kc < 4; ++kc) {
      const int k0 = kc * 64;
#pragma unroll
      for (int it = 0; it < 4; ++it) {
        int idx = it * 256 + tid;
        int row = idx >> 4, c4 = idx & 15;
        *(float4*)(&As[row][c4 * 4]) =
            *(const float4*)(Wq + (size_t)(l0 + row) * HH + k0 + c4 * 4);
        *(float4*)(&Bs[row][c4 * 4]) =
            *(const float4*)(Wk + (size_t)(i0 + row) * HH + k0 + c4 * 4);
      }
      __syncthreads();
#pragma unroll 4
      for (int k4 = 0; k4 < 16; ++k4) {
        float4 a4[4], b4[4];
#pragma unroll
        for (int r = 0; r < 4; ++r) a4[r] = *(const float4*)(&As[tl * 4 + r][k4 * 4]);
#pragma unroll
        for (int c = 0; c < 4; ++c) b4[c] = *(const float4*)(&Bs[ti * 4 + c][k4 * 4]);
#pragma unroll
        for (int r = 0; r < 4; ++r)
#pragma unroll
          for (int c = 0; c < 4; ++c)
            acc[r][c] += a4[r].x * b4[c].x + a4[r].y * b4[c].y +
                         a4[r].z * b4[c].z + a4[r].w * b4[c].w;
      }
      __syncthreads();
    }
#pragma unroll
    for (int r = 0; r < 4; ++r) {
      float4 o = make_float4(acc[r][0], acc[r][1], acc[r][2], acc[r][3]);
      *(float4*)(M2T + (size_t)(l0 + tl * 4 + r) * HH + i0 + ti * 4) = o;
    }
  } else {
    const int id = (int)blockIdx.x - 16;
    const float* row;
    const float* vec;
    float* outp;
    if (id < 256)      { row = Wk + (size_t)id * HH;         vec = bq; outp = M2T + (size_t)256 * HH + id; }
    else if (id < 512) { row = Wq + (size_t)(id - 256) * HH; vec = bk; outp = evec + (id - 256); }
    else               { row = bk;                           vec = bq; outp = fsc; }
    float p = row[tid] * vec[tid];
    p = wred_sum(p);
    if ((tid & 63) == 0) s4[tid >> 6] = p;
    __syncthreads();
    if (tid == 0) *outp = s4[0] + s4[1] + s4[2] + s4[3];
  }
}

// ---------------------------------------------------------------------------
// fused_attn: one block per b.  Phases:
//  0: cs->LDS, mask count, qb partial, hist flag + per-wave hist ballot
//  1: QK row inline from M2T (wave-split over l, LDS combine); compacted
//     valid-index list s_tl built on the same barriers (no extra syncs)
//  2: scores ONLY for compacted valid rows (8 rows in flight per wave)
//     -> X traffic drops ~250MB -> ~153MB total
//  3: softmax over compacted entries (all valid); top-8 on compacted idx
//     (compacted asc == original-t asc, preserving lax.top_k tie-break)
//  4: attn/selected outputs + gather 8 selected rows to LDS
//  5: Wv GEMV epilogue: col-split per wave, k-residue split per 16-lane
//     group -> Wv read exactly once per block (256KB, L2)
// ---------------------------------------------------------------------------
__global__ __launch_bounds__(256, 4) void fused_attn(
    const float* __restrict__ CS, const float* __restrict__ X,
    const int* __restrict__ VM,
    const float* __restrict__ M2T, const float* __restrict__ evec,
    const float* __restrict__ fsc,
    const float* __restrict__ Wv, const float* __restrict__ bvv,
    float* __restrict__ out) {
  const int tid = threadIdx.x, b = blockIdx.x;
  const int w = tid >> 6, lane = tid & 63;
  __shared__ float s_cs[HH];
  __shared__ float s_qk[HH];
  __shared__ float s_part[4][HH];
  __shared__ float s_sc[TT];
  __shared__ float s_cand[256];
  __shared__ int   s_tl[256];
  __shared__ int   s_wc[4];
  __shared__ float s_c4[4], s_r4[4], s_m4[4];
  __shared__ int   s_selI[KK];
  __shared__ float s_selV[KK];
  __shared__ float s_dS;
  __shared__ float s_xg[KK][HH + 4];

  // ---- phase 0: cs -> LDS, mask + count, qb partial ----
  const float csv = CS[(size_t)b * HH + tid];
  s_cs[tid] = csv;
  int m = (tid < TT) ? (VM[(size_t)b * TT + tid] != 0) : 0;
  unsigned long long bal = __ballot(m);
  if (lane == 0) s_c4[w] = (float)__popcll(bal);
  float rq = csv * evec[tid];
  rq = wred_sum(rq);
  if (lane == 0) s_r4[w] = rq;
  __syncthreads();

  const int cnt = (int)(s_c4[0] + s_c4[1] + s_c4[2] + s_c4[3]);
  const int hist_n = cnt - 1;            // history rows: mask && t < hist_n
  const int hist = (m && (tid < hist_n)) ? 1 : 0;
  const float qb = (s_r4[0] + s_r4[1] + s_r4[2] + s_r4[3] + fsc[0]) * 0.0625f;
  const unsigned long long bh = __ballot(hist);
  if (lane == 0) s_wc[w] = __popcll(bh);

  // ---- phase 1: QK[i] = (sum_l cs[l]*M2T[l][i] + dvec[i]) / 16 ----
  {
    float4 acc4 = make_float4(0.f, 0.f, 0.f, 0.f);
    const int l0 = w * 64;
    const float* mbase = M2T + (size_t)l0 * HH + lane * 4;
#pragma unroll 8
    for (int li = 0; li < 64; ++li) {
      const float a = s_cs[l0 + li];
      const float4 m4 = *(const float4*)(mbase + (size_t)li * HH);
      acc4.x += a * m4.x; acc4.y += a * m4.y;
      acc4.z += a * m4.z; acc4.w += a * m4.w;
    }
    *(float4*)(&s_part[w][lane * 4]) = acc4;
  }
  __syncthreads();
  const int nh = s_wc[0] + s_wc[1] + s_wc[2] + s_wc[3];
  {
    // scatter compacted valid-index list (visible after next barrier)
    int pre = 0;
#pragma unroll
    for (int i = 0; i < 4; ++i)
      if (i < w) pre += s_wc[i];
    if (hist) s_tl[pre + __popcll(bh & ((1ull << lane) - 1ull))] = tid;

    const float qk = s_part[0][tid] + s_part[1][tid] + s_part[2][tid] +
                     s_part[3][tid] + M2T[(size_t)256 * HH + tid];
    s_qk[tid] = qk * 0.0625f;
  }
  __syncthreads();

  // ---- phase 2: scores for compacted rows; wave w owns j = w, w+4, ... ----
  {
    const float* xbase = X + (size_t)b * TT * HH + lane * 4;
    const float4 q4 = ((const float4*)s_qk)[lane];
    int j = w;
    for (; j + 28 < nh; j += 32) {
      int tj[8];
#pragma unroll
      for (int u = 0; u < 8; ++u) tj[u] = s_tl[j + 4 * u];
      float4 xv[8];
#pragma unroll
      for (int u = 0; u < 8; ++u)
        xv[u] = *(const float4*)(xbase + (size_t)tj[u] * HH);
      float pr[8];
#pragma unroll
      for (int u = 0; u < 8; ++u)
        pr[u] = xv[u].x * q4.x + xv[u].y * q4.y + xv[u].z * q4.z + xv[u].w * q4.w;
#pragma unroll
      for (int off = 32; off; off >>= 1)
#pragma unroll
        for (int u = 0; u < 8; ++u) pr[u] += __shfl_xor(pr[u], off);
      if (lane == 0) {
#pragma unroll
        for (int u = 0; u < 8; ++u) s_sc[j + 4 * u] = pr[u] + qb;
      }
    }
    for (; j < nh; j += 4) {
      const int t = s_tl[j];
      float4 xv = *(const float4*)(xbase + (size_t)t * HH);
      float p = xv.x * q4.x + xv.y * q4.y + xv.z * q4.z + xv.w * q4.w;
      p = wred_sum(p);
      if (lane == 0) s_sc[j] = p + qb;
    }
  }
  __syncthreads();

  // ---- phase 3a: softmax over compacted entries (all valid) ----
  const int in_l = (tid < nh);
  float v = in_l ? s_sc[tid] : -3.4e38f;
  float wm = wred_max(v);
  if (lane == 0) s_m4[w] = wm;
  __syncthreads();
  const float mx = fmaxf(fmaxf(s_m4[0], s_m4[1]), fmaxf(s_m4[2], s_m4[3]));
  float p = in_l ? expf(v - mx) : 0.f;
  float ws_ = wred_sum(p);
  if (lane == 0) s_r4[w] = ws_;
  __syncthreads();
  const float denom = s_r4[0] + s_r4[1] + s_r4[2] + s_r4[3];
  s_cand[tid] = in_l ? (p / denom) : -2.0f;
  __syncthreads();

  // ---- phase 3b: top-8 (wave 0) over compacted entries ----
  if (tid < 64) {
    float lv[4]; int lt[4];
#pragma unroll
    for (int q = 0; q < 4; ++q) {
      int t = tid + 64 * q;
      lv[q] = s_cand[t];
      lt[q] = t;
    }
    for (int r = 0; r < KK; ++r) {
      float bv = -2.5f; int bi = 1 << 30;
#pragma unroll
      for (int q = 0; q < 4; ++q)
        if (lv[q] > bv) { bv = lv[q]; bi = lt[q]; }
#pragma unroll
      for (int off = 32; off; off >>= 1) {
        float ov = __shfl_xor(bv, off);
        int   oi = __shfl_xor(bi, off);
        if (ov > bv || (ov == bv && oi < bi)) { bv = ov; bi = oi; }
      }
      if (tid == 0) {
        s_selV[r] = bv;
        s_selI[r] = (bv >= 0.f) ? s_tl[bi] : 0;   // map back to original t
      }
#pragma unroll
      for (int q = 0; q < 4; ++q)
        if (lt[q] == bi) lv[q] = -3.0f;
    }
    if (tid == 0) {
      float S = 0.f;
#pragma unroll
      for (int r = 0; r < KK; ++r) S += fmaxf(s_selV[r], 0.f);
      s_dS = fmaxf(S, 1.1920929e-07f);
    }
  }
  __syncthreads();

  // ---- phase 4: zero attn row + gather selected rows to LDS ----
  float* out_attn = out + (size_t)BB * HH + (size_t)b * TT;
  if (tid < TT) out_attn[tid] = 0.f;
#pragma unroll
  for (int it = 0; it < 2; ++it) {
    const int r = it * 4 + (tid >> 6);
    const int t = s_selI[r];                       // 0 when invalid (weight 0)
    const int c0 = (tid & 63) * 4;
    *(float4*)(&s_xg[r][c0]) =
        *(const float4*)(X + ((size_t)b * TT + t) * HH + c0);
  }
  __syncthreads();

  if (tid < KK) {
    float vvv = s_selV[tid];
    int   bi  = s_selI[tid];
    float wf  = fmaxf(vvv, 0.f) / s_dS;
    int ok = (vvv >= 0.f);
    if (ok) out_attn[bi] = wf;
    out[(size_t)BB * HH + (size_t)BB * TT + (size_t)b * KK + tid] =
        ok ? (float)bi : -1.0f;
  }

  // ---- phase 5: summary = sum_r w_r * relu(xg[r] @ Wv + bv) ----
  // wave w owns output cols [w*64, w*64+64); lane = kk*16 + c16:
  // lane covers cols w*64 + c16*4 .. +3, k residue class kk (mod 4).
  {
    const int kk = lane >> 4, c16 = lane & 15;
    const float* wvbase = Wv + w * 64 + c16 * 4;
    float4 acc[KK];
#pragma unroll
    for (int r = 0; r < KK; ++r) acc[r] = make_float4(0.f, 0.f, 0.f, 0.f);
#pragma unroll 4
    for (int kb = 0; kb < 64; ++kb) {
      const int k = kb * 4 + kk;
      const float4 wv4 = *(const float4*)(wvbase + (size_t)k * HH);
#pragma unroll
      for (int r = 0; r < KK; ++r) {
        const float xv = s_xg[r][k];
        acc[r].x += xv * wv4.x; acc[r].y += xv * wv4.y;
        acc[r].z += xv * wv4.z; acc[r].w += xv * wv4.w;
      }
    }
    // combine the 4 k-residue groups (lanes c16, c16+16, c16+32, c16+48)
#pragma unroll
    for (int r = 0; r < KK; ++r) {
      acc[r].x += __shfl_xor(acc[r].x, 16); acc[r].x += __shfl_xor(acc[r].x, 32);
      acc[r].y += __shfl_xor(acc[r].y, 16); acc[r].y += __shfl_xor(acc[r].y, 32);
      acc[r].z += __shfl_xor(acc[r].z, 16); acc[r].z += __shfl_xor(acc[r].z, 32);
      acc[r].w += __shfl_xor(acc[r].w, 16); acc[r].w += __shfl_xor(acc[r].w, 32);
    }
    if (lane < 16) {
      const float4 bv4 = *(const float4*)(bvv + w * 64 + c16 * 4);
      float4 res = make_float4(0.f, 0.f, 0.f, 0.f);
#pragma unroll
      for (int r = 0; r < KK; ++r) {
        const float wr = fmaxf(s_selV[r], 0.f) / s_dS;
        res.x += wr * fmaxf(acc[r].x + bv4.x, 0.f);
        res.y += wr * fmaxf(acc[r].y + bv4.y, 0.f);
        res.z += wr * fmaxf(acc[r].z + bv4.z, 0.f);
        res.w += wr * fmaxf(acc[r].w + bv4.w, 0.f);
      }
      *(float4*)(out + (size_t)b * HH + w * 64 + c16 * 4) = res;
    }
  }
}

// ---------------------------------------------------------------------------
extern "C" void kernel_launch(void* const* d_in, const int* in_sizes, int n_in,
                              void* d_out, int out_size, void* d_ws, size_t ws_size,
                              hipStream_t stream) {
  const float* cs  = (const float*)d_in[0];
  const float* X   = (const float*)d_in[1];
  const int*   vm  = (const int*)d_in[2];
  const float* Wq  = (const float*)d_in[3];
  const float* bq  = (const float*)d_in[4];
  const float* Wk  = (const float*)d_in[5];
  const float* bk  = (const float*)d_in[6];
  const float* Wv  = (const float*)d_in[7];
  const float* bvp = (const float*)d_in[8];
  float* out = (float*)d_out;
  float* ws  = (float*)d_ws;

  float* M2T  = ws + WS_M2T;
  float* evec = ws + WS_EVEC;
  float* fsc  = ws + WS_F;

  hipLaunchKernelGGL(prep_all, dim3(529), dim3(256), 0, stream,
                     Wq, bq, Wk, bk, M2T, evec, fsc);
  hipLaunchKernelGGL(fused_attn, dim3(BB), dim3(256), 0, stream,
                     cs, X, vm, M2T, evec, fsc, Wv, bvp, out);
}